// Round 2
// baseline (126.709 us; speedup 1.0000x reference)
//
#include <hip/hip_runtime.h>
#include <math.h>

// Problem constants (fixed shapes from reference)
#define KNUM 256
#define HH 62
#define WW 64
#define BB 768            // N*C = 4*192
#define JV 1024           // vectors per plane = W*Hp/D = 64*64/4
#define M_TOT (BB*JV)     // 786432
#define QL_SIZE (BB*HH*WW) // 3047424

// d_out layout (concatenated tuple, float32):
#define OFF_MSE   QL_SIZE
#define OFF_INDS  (QL_SIZE + 1)
#define OFF_RATE  (OFF_INDS + M_TOT)

// d_ws layout (floats):
// [0, 2048)     codebook table: 256 entries x 8 floats {cx,cy,cz,cw, q=|c|^2+bias, l2, 0, 0}
// [2048, 2816)  per-block mse partials
// [2816, 3584)  per-block rate partials
#define WS_TAB  0
#define WS_MSE  2048
#define WS_RATE 2816

#define XT_STRIDE 65   // bank(w*65+h) = (w+h)%32 -> all phases <=2-way (conflict-free)

__global__ void vq_setup(const float* __restrict__ codebook,
                         const float* __restrict__ log_pmf,
                         float* __restrict__ ws) {
    int k = threadIdx.x;   // 256 threads
    float4 c = ((const float4*)codebook)[k];
    float l2 = log_pmf[k] * (-1.44269504088896340736f);   // log_pmf / (-ln 2)
    float q = c.x * c.x + c.y * c.y + c.z * c.z + c.w * c.w + l2 * 100.0f; // + bias/LMBDA
    float* e = ws + WS_TAB + (k << 3);
    e[0] = c.x; e[1] = c.y; e[2] = c.z; e[3] = c.w;
    e[4] = q;   e[5] = l2;  e[6] = 0.0f; e[7] = 0.0f;
}

__launch_bounds__(256)
__global__ void vq_main(const float* __restrict__ latents,
                        const float* __restrict__ codebook,
                        const float* __restrict__ log_pmf,
                        const float* __restrict__ ws_tab,
                        float* __restrict__ ws_out,
                        float* __restrict__ out) {
    __shared__ float xt[64 * XT_STRIDE];   // transposed plane [w][h], 16.6 KB
    __shared__ float4 cbv[KNUM];           // codebook rows (epilogue gather only)
    __shared__ float  l2v[KNUM];           // log2_pmf (epilogue gather only)
    __shared__ float  wred[8];

    const int t = threadIdx.x;
    const int b = blockIdx.x;
    const float* lat = latents + (size_t)b * (HH * WW);

    // ---- stage epilogue gather tables (256 threads == 256 entries) ----
    {
        float4 c = ((const float4*)codebook)[t];
        l2v[t] = log_pmf[t] * (-1.44269504088896340736f);
        cbv[t] = c;
    }

    // ---- stage latents plane transposed into LDS (pad rows 62,63 = rows 60,61) ----
    for (int idx = t; idx < (HH * WW / 4); idx += 256) {
        int h  = idx >> 4;     // row 0..61
        int wq = idx & 15;     // float4 column
        float4 v = ((const float4*)lat)[idx];
        int w0 = wq * 4;
        xt[(w0 + 0) * XT_STRIDE + h] = v.x;
        xt[(w0 + 1) * XT_STRIDE + h] = v.y;
        xt[(w0 + 2) * XT_STRIDE + h] = v.z;
        xt[(w0 + 3) * XT_STRIDE + h] = v.w;
        if (h >= 60) {     // replicate rows 60,61 -> 62,63
            int h2 = h + 2;
            xt[(w0 + 0) * XT_STRIDE + h2] = v.x;
            xt[(w0 + 1) * XT_STRIDE + h2] = v.y;
            xt[(w0 + 2) * XT_STRIDE + h2] = v.z;
            xt[(w0 + 3) * XT_STRIDE + h2] = v.w;
        }
    }
    __syncthreads();

    // ---- per-thread: 4 vectors j = t + 256*i ----
    float yx[4], yy[4], yz[4], yw[4];
    float dmin[4];
    int   kmin[4];
#pragma unroll
    for (int i = 0; i < 4; ++i) {
        int j  = t + 256 * i;
        int w  = j >> 4;
        int hc = j & 15;
        const float* p = &xt[w * XT_STRIDE + hc * 4];
        yx[i] = -2.0f * p[0];
        yy[i] = -2.0f * p[1];
        yz[i] = -2.0f * p[2];
        yw[i] = -2.0f * p[3];
        dmin[i] = INFINITY;
        kmin[i] = 0;
    }

    // ---- argmin over 256 codewords; dist = q + y.c  (y = -2x) ----
    // Codebook comes from the ws table with wave-uniform index -> scalar loads
    // (s_load) through the scalar cache; the LDS pipe stays free for xt.
#pragma unroll 4
    for (int k = 0; k < KNUM; k += 2) {
        const float* e = ws_tab + (k << 3);
        float ax = e[0], ay = e[1], az = e[2], aw = e[3], aq = e[4];
        float bx = e[8], by = e[9], bz = e[10], bw = e[11], bq = e[12];
#pragma unroll
        for (int i = 0; i < 4; ++i) {
            float d0 = fmaf(yx[i], ax, fmaf(yy[i], ay, fmaf(yz[i], az, fmaf(yw[i], aw, aq))));
            float d1 = fmaf(yx[i], bx, fmaf(yy[i], by, fmaf(yz[i], bz, fmaf(yw[i], bw, bq))));
            float nm = fminf(fminf(d0, d1), dmin[i]);   // v_min3_f32
            // first-occurrence tie-break: old index wins ties, then k before k+1
            int kp = (d0 == nm) ? k : (k + 1);
            kmin[i] = (dmin[i] == nm) ? kmin[i] : kp;
            dmin[i] = nm;
        }
    }

    // ---- epilogue per vector: gather q, accumulate mse/rate, write q in place, write ind ----
    float mse_acc = 0.0f;
    float rate_acc = 0.0f;
#pragma unroll
    for (int i = 0; i < 4; ++i) {
        int j  = t + 256 * i;
        int w  = j >> 4;
        int hc = j & 15;
        float4 c = cbv[kmin[i]];
        rate_acc += l2v[kmin[i]];
        float e0 = fmaf(0.5f, yx[i], c.x);   // c - x
        float e1 = fmaf(0.5f, yy[i], c.y);
        float e2 = fmaf(0.5f, yz[i], c.z);
        float e3 = fmaf(0.5f, yw[i], c.w);
        mse_acc += e0 * e0 + e1 * e1 + e2 * e2 + e3 * e3;
        float* p = &xt[w * XT_STRIDE + hc * 4];
        p[0] = c.x; p[1] = c.y; p[2] = c.z; p[3] = c.w;   // overwrite x with q
        out[OFF_INDS + (size_t)b * JV + j] = (float)kmin[i];
    }
    __syncthreads();

    // ---- coalesced crop/transpose write-out: ql[b, h, w] = xt[w][h], h < 62 ----
    for (int idx = t; idx < HH * WW; idx += 256) {
        int h = idx >> 6;
        int w = idx & 63;
        out[(size_t)b * (HH * WW) + idx] = xt[w * XT_STRIDE + h];
    }

    // ---- block reduction of mse/rate -> per-block partial (plain store, no atomics) ----
#pragma unroll
    for (int off = 32; off > 0; off >>= 1) {
        mse_acc  += __shfl_down(mse_acc, off, 64);
        rate_acc += __shfl_down(rate_acc, off, 64);
    }
    int wave = t >> 6, lane = t & 63;
    if (lane == 0) { wred[wave] = mse_acc; wred[4 + wave] = rate_acc; }
    __syncthreads();
    if (t == 0) {
        ws_out[WS_MSE + b]  = wred[0] + wred[1] + wred[2] + wred[3];
        ws_out[WS_RATE + b] = wred[4] + wred[5] + wred[6] + wred[7];
    }
}

__global__ void vq_reduce(const float* __restrict__ ws, float* __restrict__ out) {
    __shared__ float wred[8];
    int t = threadIdx.x;   // 256 threads
    float m = ws[WS_MSE + t]  + ws[WS_MSE + 256 + t]  + ws[WS_MSE + 512 + t];
    float r = ws[WS_RATE + t] + ws[WS_RATE + 256 + t] + ws[WS_RATE + 512 + t];
#pragma unroll
    for (int off = 32; off > 0; off >>= 1) {
        m += __shfl_down(m, off, 64);
        r += __shfl_down(r, off, 64);
    }
    int wave = t >> 6, lane = t & 63;
    if (lane == 0) { wred[wave] = m; wred[4 + wave] = r; }
    __syncthreads();
    if (t == 0) {
        out[OFF_MSE]      = (wred[0] + wred[1] + wred[2] + wred[3]) * (1.0f / 3145728.0f);
        out[OFF_RATE]     = wred[4] + wred[5] + wred[6] + wred[7];
        out[OFF_RATE + 1] = 0.0f;
        out[OFF_RATE + 2] = 0.0f;
    }
}

extern "C" void kernel_launch(void* const* d_in, const int* in_sizes, int n_in,
                              void* d_out, int out_size, void* d_ws, size_t ws_size,
                              hipStream_t stream) {
    const float* latents  = (const float*)d_in[0];
    const float* codebook = (const float*)d_in[1];
    const float* log_pmf  = (const float*)d_in[2];
    float* out = (float*)d_out;
    float* ws  = (float*)d_ws;

    vq_setup<<<1, 256, 0, stream>>>(codebook, log_pmf, ws);
    vq_main<<<BB, 256, 0, stream>>>(latents, codebook, log_pmf, ws, ws, out);
    vq_reduce<<<1, 256, 0, stream>>>(ws, out);
}

// Round 3
// 115.669 us; speedup vs baseline: 1.0954x; 1.0954x over previous
//
#include <hip/hip_runtime.h>
#include <math.h>

// Problem constants (fixed shapes from reference)
#define KNUM 256
#define HH 62
#define WW 64
#define BB 768            // N*C = 4*192
#define JV 1024           // vectors per plane = W*Hp/D = 64*64/4
#define M_TOT (BB*JV)     // 786432
#define QL_SIZE (BB*HH*WW) // 3047424

// d_out layout (concatenated tuple, float32):
#define OFF_MSE   QL_SIZE
#define OFF_INDS  (QL_SIZE + 1)
#define OFF_RATE  (OFF_INDS + M_TOT)

// d_ws layout (floats): per-block partials
#define WS_MSE  0
#define WS_RATE 768

#define XT_STRIDE 65   // bank(w*65+h) = (w+h)%32 -> all phases <=2-way (conflict-free)

// 128 threads/block, 8 vectors/thread: halves waves/CU vs 256x4 so the
// per-CU LDS pipe (codebook broadcast reads) stops being the bottleneck;
// VALU work per SIMD is unchanged -> VALU-bound.
__launch_bounds__(128)
__global__ void vq_main(const float* __restrict__ latents,
                        const float* __restrict__ codebook,
                        const float* __restrict__ log_pmf,
                        float* __restrict__ ws_out,
                        float* __restrict__ out) {
    __shared__ float xt[64 * XT_STRIDE];   // transposed plane [w][h], 16.6 KB
    __shared__ float4 cbv[KNUM];           // codebook rows
    __shared__ float  cck[KNUM];           // ||c||^2 + rate_bias
    __shared__ float  l2v[KNUM];           // log2_pmf
    __shared__ float  wred[4];

    const int t = threadIdx.x;
    const int b = blockIdx.x;
    const float* lat = latents + (size_t)b * (HH * WW);

    // ---- stage codebook tables (128 threads, 2 entries each) ----
#pragma unroll
    for (int kk = 0; kk < 2; ++kk) {
        int k = t + 128 * kk;
        float4 c = ((const float4*)codebook)[k];
        float l2 = log_pmf[k] * (-1.44269504088896340736f);   // log_pmf / (-ln 2)
        l2v[k] = l2;
        cck[k] = c.x * c.x + c.y * c.y + c.z * c.z + c.w * c.w + l2 * 100.0f; // /LMBDA
        cbv[k] = c;
    }

    // ---- stage latents plane transposed into LDS (pad rows 62,63 = rows 60,61) ----
    for (int idx = t; idx < (HH * WW / 4); idx += 128) {
        int h  = idx >> 4;     // row 0..61
        int wq = idx & 15;     // float4 column
        float4 v = ((const float4*)lat)[idx];
        int w0 = wq * 4;
        xt[(w0 + 0) * XT_STRIDE + h] = v.x;
        xt[(w0 + 1) * XT_STRIDE + h] = v.y;
        xt[(w0 + 2) * XT_STRIDE + h] = v.z;
        xt[(w0 + 3) * XT_STRIDE + h] = v.w;
        if (h >= 60) {     // replicate rows 60,61 -> 62,63
            int h2 = h + 2;
            xt[(w0 + 0) * XT_STRIDE + h2] = v.x;
            xt[(w0 + 1) * XT_STRIDE + h2] = v.y;
            xt[(w0 + 2) * XT_STRIDE + h2] = v.z;
            xt[(w0 + 3) * XT_STRIDE + h2] = v.w;
        }
    }
    __syncthreads();

    // ---- per-thread: 8 vectors j = t + 128*i ----
    float yx[8], yy[8], yz[8], yw[8];
    float dmin[8];
    int   kmin[8];
#pragma unroll
    for (int i = 0; i < 8; ++i) {
        int j  = t + 128 * i;
        int w  = j >> 4;
        int hc = j & 15;
        const float* p = &xt[w * XT_STRIDE + hc * 4];
        yx[i] = -2.0f * p[0];
        yy[i] = -2.0f * p[1];
        yz[i] = -2.0f * p[2];
        yw[i] = -2.0f * p[3];
        dmin[i] = INFINITY;
        kmin[i] = 0;
    }

    // ---- argmin over 256 codewords; dist = cck[k] + y.c  (y = -2x) ----
    // LDS broadcast reads (same address wave-wide = conflict-free), amortized
    // over 8 vectors per thread.
#pragma unroll 4
    for (int k = 0; k < KNUM; k += 2) {
        float4 ca = cbv[k];
        float  qa = cck[k];
        float4 cb = cbv[k + 1];
        float  qb = cck[k + 1];
#pragma unroll
        for (int i = 0; i < 8; ++i) {
            float d0 = fmaf(yx[i], ca.x, fmaf(yy[i], ca.y, fmaf(yz[i], ca.z, fmaf(yw[i], ca.w, qa))));
            float d1 = fmaf(yx[i], cb.x, fmaf(yy[i], cb.y, fmaf(yz[i], cb.z, fmaf(yw[i], cb.w, qb))));
            float nm = fminf(fminf(d0, d1), dmin[i]);   // v_min3_f32
            // first-occurrence tie-break: old index wins ties, then k before k+1
            int kp = (d0 == nm) ? k : (k + 1);
            kmin[i] = (dmin[i] == nm) ? kmin[i] : kp;
            dmin[i] = nm;
        }
    }

    // ---- epilogue per vector: gather q, accumulate mse/rate, write q in place, write ind ----
    float mse_acc = 0.0f;
    float rate_acc = 0.0f;
#pragma unroll
    for (int i = 0; i < 8; ++i) {
        int j  = t + 128 * i;
        int w  = j >> 4;
        int hc = j & 15;
        float4 c = cbv[kmin[i]];
        rate_acc += l2v[kmin[i]];
        float e0 = fmaf(0.5f, yx[i], c.x);   // c - x
        float e1 = fmaf(0.5f, yy[i], c.y);
        float e2 = fmaf(0.5f, yz[i], c.z);
        float e3 = fmaf(0.5f, yw[i], c.w);
        mse_acc += e0 * e0 + e1 * e1 + e2 * e2 + e3 * e3;
        float* p = &xt[w * XT_STRIDE + hc * 4];
        p[0] = c.x; p[1] = c.y; p[2] = c.z; p[3] = c.w;   // overwrite x with q
        out[OFF_INDS + (size_t)b * JV + j] = (float)kmin[i];
    }
    __syncthreads();

    // ---- coalesced crop/transpose write-out: ql[b, h, w] = xt[w][h], h < 62 ----
    for (int idx = t; idx < HH * WW; idx += 128) {
        int h = idx >> 6;
        int w = idx & 63;
        out[(size_t)b * (HH * WW) + idx] = xt[w * XT_STRIDE + h];
    }

    // ---- block reduction of mse/rate -> per-block partial (plain store) ----
#pragma unroll
    for (int off = 32; off > 0; off >>= 1) {
        mse_acc  += __shfl_down(mse_acc, off, 64);
        rate_acc += __shfl_down(rate_acc, off, 64);
    }
    int wave = t >> 6, lane = t & 63;
    if (lane == 0) { wred[wave] = mse_acc; wred[2 + wave] = rate_acc; }
    __syncthreads();
    if (t == 0) {
        ws_out[WS_MSE + b]  = wred[0] + wred[1];
        ws_out[WS_RATE + b] = wred[2] + wred[3];
    }
}

__global__ void vq_reduce(const float* __restrict__ ws, float* __restrict__ out) {
    __shared__ float wred[8];
    int t = threadIdx.x;   // 256 threads
    float m = ws[WS_MSE + t]  + ws[WS_MSE + 256 + t]  + ws[WS_MSE + 512 + t];
    float r = ws[WS_RATE + t] + ws[WS_RATE + 256 + t] + ws[WS_RATE + 512 + t];
#pragma unroll
    for (int off = 32; off > 0; off >>= 1) {
        m += __shfl_down(m, off, 64);
        r += __shfl_down(r, off, 64);
    }
    int wave = t >> 6, lane = t & 63;
    if (lane == 0) { wred[wave] = m; wred[4 + wave] = r; }
    __syncthreads();
    if (t == 0) {
        out[OFF_MSE]      = (wred[0] + wred[1] + wred[2] + wred[3]) * (1.0f / 3145728.0f);
        out[OFF_RATE]     = wred[4] + wred[5] + wred[6] + wred[7];
        out[OFF_RATE + 1] = 0.0f;
        out[OFF_RATE + 2] = 0.0f;
    }
}

extern "C" void kernel_launch(void* const* d_in, const int* in_sizes, int n_in,
                              void* d_out, int out_size, void* d_ws, size_t ws_size,
                              hipStream_t stream) {
    const float* latents  = (const float*)d_in[0];
    const float* codebook = (const float*)d_in[1];
    const float* log_pmf  = (const float*)d_in[2];
    float* out = (float*)d_out;
    float* ws  = (float*)d_ws;

    vq_main<<<BB, 128, 0, stream>>>(latents, codebook, log_pmf, ws, out);
    vq_reduce<<<1, 256, 0, stream>>>(ws, out);
}

// Round 4
// 111.290 us; speedup vs baseline: 1.1385x; 1.0393x over previous
//
#include <hip/hip_runtime.h>
#include <math.h>

// Problem constants (fixed shapes from reference)
#define KNUM 256
#define HH 62
#define WW 64
#define BB 768            // N*C = 4*192
#define JV 1024           // vectors per plane = W*Hp/D = 64*64/4
#define M_TOT (BB*JV)     // 786432
#define QL_SIZE (BB*HH*WW) // 3047424

// d_out layout (concatenated tuple, float32):
#define OFF_MSE   QL_SIZE
#define OFF_INDS  (QL_SIZE + 1)
#define OFF_RATE  (OFF_INDS + M_TOT)

// d_ws layout (floats): per-block partials
#define WS_MSE  0
#define WS_RATE 768

#define XT_STRIDE 65   // bank(w*65+h) = (w+h)%32 -> all phases <=2-way (conflict-free)

typedef float v2f __attribute__((ext_vector_type(2)));

// Packed fp32 FMA: d = a*b + c on both halves. gfx90a+/gfx950 VOP3P.
__device__ __forceinline__ v2f pk_fma(v2f a, v2f b, v2f c) {
    v2f d;
    asm("v_pk_fma_f32 %0, %1, %2, %3" : "=v"(d) : "v"(a), "v"(b), "v"(c));
    return d;
}
__device__ __forceinline__ v2f pk_fma_acc(v2f a, v2f b, v2f d) {
    asm("v_pk_fma_f32 %0, %1, %2, %0" : "+v"(d) : "v"(a), "v"(b));
    return d;
}

// 768 blocks x 128 threads, 8 vectors/thread. (128,1): let VGPRs grow (R3's
// default heuristic capped at 52 VGPR -> reloads). Grid-limited 3 blocks/CU.
__launch_bounds__(128, 1)
__global__ void vq_main(const float* __restrict__ latents,
                        const float* __restrict__ codebook,
                        const float* __restrict__ log_pmf,
                        float* __restrict__ ws_out,
                        float* __restrict__ out) {
    __shared__ __align__(16) float xt[64 * XT_STRIDE];  // transposed plane [w][h]
    __shared__ __align__(16) float tab[128 * 10];       // pair-interleaved codebook
    __shared__ float4 cbv[KNUM];                        // epilogue gather
    __shared__ float  l2v[KNUM];
    __shared__ float  wred[4];

    const int t = threadIdx.x;
    const int b = blockIdx.x;
    const float* lat = latents + (size_t)b * (HH * WW);

    // ---- stage pair-interleaved codebook table (128 threads == 128 pairs) ----
    {
        float4 c0 = ((const float4*)codebook)[2 * t];
        float4 c1 = ((const float4*)codebook)[2 * t + 1];
        float l20 = log_pmf[2 * t]     * (-1.44269504088896340736f);
        float l21 = log_pmf[2 * t + 1] * (-1.44269504088896340736f);
        float q0 = c0.x * c0.x + c0.y * c0.y + c0.z * c0.z + c0.w * c0.w + l20 * 100.0f;
        float q1 = c1.x * c1.x + c1.y * c1.y + c1.z * c1.z + c1.w * c1.w + l21 * 100.0f;
        float* e = &tab[t * 10];
        e[0] = c0.x; e[1] = c1.x;
        e[2] = c0.y; e[3] = c1.y;
        e[4] = c0.z; e[5] = c1.z;
        e[6] = c0.w; e[7] = c1.w;
        e[8] = q0;   e[9] = q1;
        cbv[2 * t] = c0; cbv[2 * t + 1] = c1;
        l2v[2 * t] = l20; l2v[2 * t + 1] = l21;
    }

    // ---- stage latents plane transposed into LDS (pad rows 62,63 = rows 60,61) ----
    for (int idx = t; idx < (HH * WW / 4); idx += 128) {
        int h  = idx >> 4;     // row 0..61
        int wq = idx & 15;     // float4 column
        float4 v = ((const float4*)lat)[idx];
        int w0 = wq * 4;
        xt[(w0 + 0) * XT_STRIDE + h] = v.x;
        xt[(w0 + 1) * XT_STRIDE + h] = v.y;
        xt[(w0 + 2) * XT_STRIDE + h] = v.z;
        xt[(w0 + 3) * XT_STRIDE + h] = v.w;
        if (h >= 60) {     // replicate rows 60,61 -> 62,63
            int h2 = h + 2;
            xt[(w0 + 0) * XT_STRIDE + h2] = v.x;
            xt[(w0 + 1) * XT_STRIDE + h2] = v.y;
            xt[(w0 + 2) * XT_STRIDE + h2] = v.z;
            xt[(w0 + 3) * XT_STRIDE + h2] = v.w;
        }
    }
    __syncthreads();

    // ---- per-thread: 8 vectors j = t + 128*i; y = -2x kept as splat pairs ----
    v2f ysx[8], ysy[8], ysz[8], ysw[8];
    float dmin[8];
    int   kmin[8];
#pragma unroll
    for (int i = 0; i < 8; ++i) {
        int j  = t + 128 * i;
        int w  = j >> 4;
        int hc = j & 15;
        const float* p = &xt[w * XT_STRIDE + hc * 4];
        float ax = -2.0f * p[0], ay = -2.0f * p[1], az = -2.0f * p[2], aw = -2.0f * p[3];
        ysx[i] = (v2f){ax, ax};
        ysy[i] = (v2f){ay, ay};
        ysz[i] = (v2f){az, az};
        ysw[i] = (v2f){aw, aw};
        dmin[i] = INFINITY;
        kmin[i] = 0;
    }

    // ---- argmin over 256 codewords, 2 at a time via packed fp32 FMA ----
    // dist pair d2 = {q0,q1} + sum_c y_c * {c0,c1}; LDS reads are wave-uniform
    // broadcasts amortized over 8 vectors.
#pragma unroll 4
    for (int k2 = 0; k2 < 128; ++k2) {
        const float* e = &tab[k2 * 10];
        v2f cx2 = *(const v2f*)(e + 0);
        v2f cy2 = *(const v2f*)(e + 2);
        v2f cz2 = *(const v2f*)(e + 4);
        v2f cw2 = *(const v2f*)(e + 6);
        v2f qq  = *(const v2f*)(e + 8);
        int k = k2 * 2;
#pragma unroll
        for (int i = 0; i < 8; ++i) {
            v2f d2 = pk_fma(cx2, ysx[i], qq);
            d2 = pk_fma_acc(cy2, ysy[i], d2);
            d2 = pk_fma_acc(cz2, ysz[i], d2);
            d2 = pk_fma_acc(cw2, ysw[i], d2);
            float nm = fminf(fminf(d2.x, d2.y), dmin[i]);   // v_min3_f32
            // first-occurrence tie-break: old index wins ties, then k before k+1
            int kp = (d2.x == nm) ? k : (k + 1);
            kmin[i] = (dmin[i] == nm) ? kmin[i] : kp;
            dmin[i] = nm;
        }
    }

    // ---- epilogue per vector: gather q, accumulate mse/rate, write q in place, write ind ----
    float mse_acc = 0.0f;
    float rate_acc = 0.0f;
#pragma unroll
    for (int i = 0; i < 8; ++i) {
        int j  = t + 128 * i;
        int w  = j >> 4;
        int hc = j & 15;
        float4 c = cbv[kmin[i]];
        rate_acc += l2v[kmin[i]];
        float e0 = fmaf(0.5f, ysx[i].x, c.x);   // c - x
        float e1 = fmaf(0.5f, ysy[i].x, c.y);
        float e2 = fmaf(0.5f, ysz[i].x, c.z);
        float e3 = fmaf(0.5f, ysw[i].x, c.w);
        mse_acc += e0 * e0 + e1 * e1 + e2 * e2 + e3 * e3;
        float* p = &xt[w * XT_STRIDE + hc * 4];
        p[0] = c.x; p[1] = c.y; p[2] = c.z; p[3] = c.w;   // overwrite x with q
        out[OFF_INDS + (size_t)b * JV + j] = (float)kmin[i];
    }
    __syncthreads();

    // ---- coalesced crop/transpose write-out: ql[b, h, w] = xt[w][h], h < 62 ----
    for (int idx = t; idx < HH * WW; idx += 128) {
        int h = idx >> 6;
        int w = idx & 63;
        out[(size_t)b * (HH * WW) + idx] = xt[w * XT_STRIDE + h];
    }

    // ---- block reduction of mse/rate -> per-block partial (plain store) ----
#pragma unroll
    for (int off = 32; off > 0; off >>= 1) {
        mse_acc  += __shfl_down(mse_acc, off, 64);
        rate_acc += __shfl_down(rate_acc, off, 64);
    }
    int wave = t >> 6, lane = t & 63;
    if (lane == 0) { wred[wave] = mse_acc; wred[2 + wave] = rate_acc; }
    __syncthreads();
    if (t == 0) {
        ws_out[WS_MSE + b]  = wred[0] + wred[1];
        ws_out[WS_RATE + b] = wred[2] + wred[3];
    }
}

__global__ void vq_reduce(const float* __restrict__ ws, float* __restrict__ out) {
    __shared__ float wred[8];
    int t = threadIdx.x;   // 256 threads
    float m = ws[WS_MSE + t]  + ws[WS_MSE + 256 + t]  + ws[WS_MSE + 512 + t];
    float r = ws[WS_RATE + t] + ws[WS_RATE + 256 + t] + ws[WS_RATE + 512 + t];
#pragma unroll
    for (int off = 32; off > 0; off >>= 1) {
        m += __shfl_down(m, off, 64);
        r += __shfl_down(r, off, 64);
    }
    int wave = t >> 6, lane = t & 63;
    if (lane == 0) { wred[wave] = m; wred[4 + wave] = r; }
    __syncthreads();
    if (t == 0) {
        out[OFF_MSE]      = (wred[0] + wred[1] + wred[2] + wred[3]) * (1.0f / 3145728.0f);
        out[OFF_RATE]     = wred[4] + wred[5] + wred[6] + wred[7];
        out[OFF_RATE + 1] = 0.0f;
        out[OFF_RATE + 2] = 0.0f;
    }
}

extern "C" void kernel_launch(void* const* d_in, const int* in_sizes, int n_in,
                              void* d_out, int out_size, void* d_ws, size_t ws_size,
                              hipStream_t stream) {
    const float* latents  = (const float*)d_in[0];
    const float* codebook = (const float*)d_in[1];
    const float* log_pmf  = (const float*)d_in[2];
    float* out = (float*)d_out;
    float* ws  = (float*)d_ws;

    vq_main<<<BB, 128, 0, stream>>>(latents, codebook, log_pmf, ws, out);
    vq_reduce<<<1, 256, 0, stream>>>(ws, out);
}

// Round 5
// 98.682 us; speedup vs baseline: 1.2840x; 1.1278x over previous
//
#include <hip/hip_runtime.h>
#include <math.h>

// Problem constants (fixed shapes from reference)
#define KNUM 256
#define HH 62
#define WW 64
#define BB 768            // N*C = 4*192
#define JV 1024           // vectors per plane = W*Hp/D = 64*64/4
#define M_TOT (BB*JV)     // 786432
#define QL_SIZE (BB*HH*WW) // 3047424

// d_out layout (concatenated tuple, float32):
#define OFF_MSE   QL_SIZE
#define OFF_INDS  (QL_SIZE + 1)
#define OFF_RATE  (OFF_INDS + M_TOT)

// d_ws layout (floats): per-block partials
#define WS_MSE  0
#define WS_RATE 768

#define XT_STRIDE 65   // bank(w*65+h) = (w+h)%32 -> all phases <=2-way (conflict-free)

typedef float v2f __attribute__((ext_vector_type(2)));

// v_pk_fma_f32 d = c*y + acc, with src1 (y) broadcast from ONE 32-bit half to
// both output halves via op_sel/op_sel_hi -> y needs no splat registers.
// lo-broadcast: lo half reads y.lo (op_sel[1]=0), hi half reads y.lo (op_sel_hi[1]=0)
// hi-broadcast: lo half reads y.hi (op_sel[1]=1), hi half reads y.hi (op_sel_hi[1]=1)
__device__ __forceinline__ v2f pk_fma_ylo(v2f c, v2f y, v2f acc) {
    v2f d;
    asm("v_pk_fma_f32 %0, %1, %2, %3 op_sel:[0,0,0] op_sel_hi:[1,0,1]"
        : "=v"(d) : "v"(c), "v"(y), "v"(acc));
    return d;
}
__device__ __forceinline__ v2f pk_fma_ylo_acc(v2f c, v2f y, v2f d) {
    asm("v_pk_fma_f32 %0, %1, %2, %0 op_sel:[0,0,0] op_sel_hi:[1,0,1]"
        : "+v"(d) : "v"(c), "v"(y));
    return d;
}
__device__ __forceinline__ v2f pk_fma_yhi_acc(v2f c, v2f y, v2f d) {
    asm("v_pk_fma_f32 %0, %1, %2, %0 op_sel:[0,1,0] op_sel_hi:[1,1,1]"
        : "+v"(d) : "v"(c), "v"(y));
    return d;
}

// 768 blocks x 256 threads, 4 vectors/thread: 3 blocks/CU, 3 waves/SIMD for
// latency hiding; (256,4) caps VGPR at 128 (keeps 3 blocks resident) without
// strangling the allocator (R4: heuristic gave 68 -> remat movs everywhere).
__launch_bounds__(256, 4)
__global__ void vq_main(const float* __restrict__ latents,
                        const float* __restrict__ codebook,
                        const float* __restrict__ log_pmf,
                        float* __restrict__ ws_out,
                        float* __restrict__ out) {
    __shared__ __align__(16) float xt[64 * XT_STRIDE];  // transposed plane [w][h]
    __shared__ __align__(16) float tab[128 * 10];       // pair-interleaved codebook
    __shared__ float4 cbv[KNUM];                        // epilogue gather
    __shared__ float  l2v[KNUM];
    __shared__ float  wred[8];

    const int t = threadIdx.x;
    const int b = blockIdx.x;
    const float* lat = latents + (size_t)b * (HH * WW);

    // ---- stage pair-interleaved codebook table (first 128 threads) ----
    if (t < 128) {
        float4 c0 = ((const float4*)codebook)[2 * t];
        float4 c1 = ((const float4*)codebook)[2 * t + 1];
        float l20 = log_pmf[2 * t]     * (-1.44269504088896340736f);
        float l21 = log_pmf[2 * t + 1] * (-1.44269504088896340736f);
        float q0 = c0.x * c0.x + c0.y * c0.y + c0.z * c0.z + c0.w * c0.w + l20 * 100.0f;
        float q1 = c1.x * c1.x + c1.y * c1.y + c1.z * c1.z + c1.w * c1.w + l21 * 100.0f;
        float* e = &tab[t * 10];
        e[0] = c0.x; e[1] = c1.x;
        e[2] = c0.y; e[3] = c1.y;
        e[4] = c0.z; e[5] = c1.z;
        e[6] = c0.w; e[7] = c1.w;
        e[8] = q0;   e[9] = q1;
        cbv[2 * t] = c0; cbv[2 * t + 1] = c1;
        l2v[2 * t] = l20; l2v[2 * t + 1] = l21;
    }

    // ---- stage latents plane transposed into LDS (pad rows 62,63 = rows 60,61) ----
    for (int idx = t; idx < (HH * WW / 4); idx += 256) {
        int h  = idx >> 4;     // row 0..61
        int wq = idx & 15;     // float4 column
        float4 v = ((const float4*)lat)[idx];
        int w0 = wq * 4;
        xt[(w0 + 0) * XT_STRIDE + h] = v.x;
        xt[(w0 + 1) * XT_STRIDE + h] = v.y;
        xt[(w0 + 2) * XT_STRIDE + h] = v.z;
        xt[(w0 + 3) * XT_STRIDE + h] = v.w;
        if (h >= 60) {     // replicate rows 60,61 -> 62,63
            int h2 = h + 2;
            xt[(w0 + 0) * XT_STRIDE + h2] = v.x;
            xt[(w0 + 1) * XT_STRIDE + h2] = v.y;
            xt[(w0 + 2) * XT_STRIDE + h2] = v.z;
            xt[(w0 + 3) * XT_STRIDE + h2] = v.w;
        }
    }
    __syncthreads();

    // ---- per-thread: 4 vectors j = t + 256*i; y = -2x as natural pairs ----
    v2f y01[4], y23[4];    // {yx,yy}, {yz,yw} -- 4 VGPRs per vector
    float dmin[4];
    int   kmin[4];
#pragma unroll
    for (int i = 0; i < 4; ++i) {
        int j  = t + 256 * i;
        int w  = j >> 4;
        int hc = j & 15;
        const float* p = &xt[w * XT_STRIDE + hc * 4];
        y01[i] = (v2f){-2.0f * p[0], -2.0f * p[1]};
        y23[i] = (v2f){-2.0f * p[2], -2.0f * p[3]};
        dmin[i] = INFINITY;
        kmin[i] = 0;
    }

    // ---- argmin over 256 codewords, 2 at a time via packed fp32 FMA ----
    // dist pair d2 = {q0,q1} + sum_c y_c * {c0,c1}; tab reads are wave-uniform
    // LDS broadcasts (conflict-free) amortized over 4 vectors.
#pragma unroll 4
    for (int k2 = 0; k2 < 128; ++k2) {
        const float* e = &tab[k2 * 10];
        v2f cx2 = *(const v2f*)(e + 0);
        v2f cy2 = *(const v2f*)(e + 2);
        v2f cz2 = *(const v2f*)(e + 4);
        v2f cw2 = *(const v2f*)(e + 6);
        v2f qq  = *(const v2f*)(e + 8);
        int k = k2 * 2;
#pragma unroll
        for (int i = 0; i < 4; ++i) {
            v2f d2 = pk_fma_ylo(cx2, y01[i], qq);        // + yx*{cx0,cx1}
            d2 = pk_fma_yhi_acc(cy2, y01[i], d2);        // + yy*{cy0,cy1}
            d2 = pk_fma_ylo_acc(cz2, y23[i], d2);        // + yz*{cz0,cz1}
            d2 = pk_fma_yhi_acc(cw2, y23[i], d2);        // + yw*{cw0,cw1}
            float nm = fminf(fminf(d2.x, d2.y), dmin[i]);   // v_min3_f32
            // first-occurrence tie-break: old index wins ties, then k before k+1
            int kp = (d2.x == nm) ? k : (k + 1);
            kmin[i] = (dmin[i] == nm) ? kmin[i] : kp;
            dmin[i] = nm;
        }
    }

    // ---- epilogue per vector: gather q, accumulate mse/rate, write q in place, write ind ----
    float mse_acc = 0.0f;
    float rate_acc = 0.0f;
#pragma unroll
    for (int i = 0; i < 4; ++i) {
        int j  = t + 256 * i;
        int w  = j >> 4;
        int hc = j & 15;
        float4 c = cbv[kmin[i]];
        rate_acc += l2v[kmin[i]];
        float e0 = fmaf(0.5f, y01[i].x, c.x);   // c - x
        float e1 = fmaf(0.5f, y01[i].y, c.y);
        float e2 = fmaf(0.5f, y23[i].x, c.z);
        float e3 = fmaf(0.5f, y23[i].y, c.w);
        mse_acc += e0 * e0 + e1 * e1 + e2 * e2 + e3 * e3;
        float* p = &xt[w * XT_STRIDE + hc * 4];
        p[0] = c.x; p[1] = c.y; p[2] = c.z; p[3] = c.w;   // overwrite x with q
        out[OFF_INDS + (size_t)b * JV + j] = (float)kmin[i];
    }
    __syncthreads();

    // ---- coalesced crop/transpose write-out: ql[b, h, w] = xt[w][h], h < 62 ----
    for (int idx = t; idx < HH * WW; idx += 256) {
        int h = idx >> 6;
        int w = idx & 63;
        out[(size_t)b * (HH * WW) + idx] = xt[w * XT_STRIDE + h];
    }

    // ---- block reduction of mse/rate -> per-block partial (plain store) ----
#pragma unroll
    for (int off = 32; off > 0; off >>= 1) {
        mse_acc  += __shfl_down(mse_acc, off, 64);
        rate_acc += __shfl_down(rate_acc, off, 64);
    }
    int wave = t >> 6, lane = t & 63;
    if (lane == 0) { wred[wave] = mse_acc; wred[4 + wave] = rate_acc; }
    __syncthreads();
    if (t == 0) {
        ws_out[WS_MSE + b]  = wred[0] + wred[1] + wred[2] + wred[3];
        ws_out[WS_RATE + b] = wred[4] + wred[5] + wred[6] + wred[7];
    }
}

__global__ void vq_reduce(const float* __restrict__ ws, float* __restrict__ out) {
    __shared__ float wred[8];
    int t = threadIdx.x;   // 256 threads
    float m = ws[WS_MSE + t]  + ws[WS_MSE + 256 + t]  + ws[WS_MSE + 512 + t];
    float r = ws[WS_RATE + t] + ws[WS_RATE + 256 + t] + ws[WS_RATE + 512 + t];
#pragma unroll
    for (int off = 32; off > 0; off >>= 1) {
        m += __shfl_down(m, off, 64);
        r += __shfl_down(r, off, 64);
    }
    int wave = t >> 6, lane = t & 63;
    if (lane == 0) { wred[wave] = m; wred[4 + wave] = r; }
    __syncthreads();
    if (t == 0) {
        out[OFF_MSE]      = (wred[0] + wred[1] + wred[2] + wred[3]) * (1.0f / 3145728.0f);
        out[OFF_RATE]     = wred[4] + wred[5] + wred[6] + wred[7];
        out[OFF_RATE + 1] = 0.0f;
        out[OFF_RATE + 2] = 0.0f;
    }
}

extern "C" void kernel_launch(void* const* d_in, const int* in_sizes, int n_in,
                              void* d_out, int out_size, void* d_ws, size_t ws_size,
                              hipStream_t stream) {
    const float* latents  = (const float*)d_in[0];
    const float* codebook = (const float*)d_in[1];
    const float* log_pmf  = (const float*)d_in[2];
    float* out = (float*)d_out;
    float* ws  = (float*)d_ws;

    vq_main<<<BB, 256, 0, stream>>>(latents, codebook, log_pmf, ws, out);
    vq_reduce<<<1, 256, 0, stream>>>(ws, out);
}